// Round 4
// baseline (989.582 us; speedup 1.0000x reference)
//
#include <hip/hip_runtime.h>
#include <math.h>

typedef __attribute__((ext_vector_type(8))) short bf16x8;
typedef __attribute__((ext_vector_type(4))) float f32x4;

__device__ __forceinline__ short f2bf(float v) {
  union { float f; unsigned u; } x; x.f = v;
  unsigned r = x.u + 0x7fffu + ((x.u >> 16) & 1u);
  return (short)(r >> 16);
}

__device__ __forceinline__ float bf2f(unsigned short u) {
  union { unsigned u; float f; } x; x.u = ((unsigned)u) << 16;
  return x.f;
}

__device__ __forceinline__ void gld_lds16(const void* g, void* l) {
  __builtin_amdgcn_global_load_lds((const __attribute__((address_space(1))) void*)g,
                                   (__attribute__((address_space(3))) void*)l, 16, 0, 0);
}

// ---------------- transpose fp32 [R,C] -> bf16 [C,R], batched over z ----------------
__global__ __launch_bounds__(256) void transpose_bf(const float* __restrict__ src,
                                                    short* __restrict__ dst,
                                                    int R, int C, size_t sStride, size_t dStride) {
  __shared__ float t[32][33];
  src += blockIdx.z * sStride;
  dst += blockIdx.z * dStride;
  int tx = threadIdx.x & 31, ty = threadIdx.x >> 5;  // 32 x 8
  int c0 = blockIdx.x * 32, r0 = blockIdx.y * 32;
#pragma unroll
  for (int i = 0; i < 4; i++)
    t[ty + i * 8][tx] = src[(size_t)(r0 + ty + i * 8) * C + c0 + tx];
  __syncthreads();
#pragma unroll
  for (int i = 0; i < 4; i++)
    dst[(size_t)(c0 + ty + i * 8) * R + r0 + tx] = f2bf(t[tx][ty + i * 8]);
}

// ---------------- transpose Wq/Wk/Wv [512,512] fp32 -> qkvt bf16, one dispatch ----------------
__global__ __launch_bounds__(256) void transpose_qkv(const float* __restrict__ Wq,
                                                     const float* __restrict__ Wk,
                                                     const float* __restrict__ Wv,
                                                     short* __restrict__ qkvt) {
  __shared__ float t[32][33];
  const int z = blockIdx.z;           // 0..17
  const int which = z / 6, l = z % 6;
  const float* src = (which == 0 ? Wq : which == 1 ? Wk : Wv) + (size_t)l * 262144;
  short* dst = qkvt + (size_t)l * 786432 + (size_t)which * 262144;
  int tx = threadIdx.x & 31, ty = threadIdx.x >> 5;
  int c0 = blockIdx.x * 32, r0 = blockIdx.y * 32;
#pragma unroll
  for (int i = 0; i < 4; i++)
    t[ty + i * 8][tx] = src[(size_t)(r0 + ty + i * 8) * 512 + c0 + tx];
  __syncthreads();
#pragma unroll
  for (int i = 0; i < 4; i++)
    dst[(size_t)(c0 + ty + i * 8) * 512 + r0 + tx] = f2bf(t[tx][ty + i * 8]);
}

// ---------------- embed: h = x @ W_in + b_in + pe; also bf16 copy ----------------
__global__ void embed_kernel(const float* __restrict__ x, const float* __restrict__ W_in,
                             const float* __restrict__ b_in, const float* __restrict__ pe,
                             float* __restrict__ h, short* __restrict__ hbf) {
  int col = (blockIdx.x & 1) * 256 + threadIdx.x;
  int row = blockIdx.x >> 1;
  int s = row & 511;
  float a = b_in[col] + pe[s * 512 + col];
  const float* xr = x + (size_t)row * 32;
#pragma unroll
  for (int k = 0; k < 32; k++) a += xr[k] * W_in[k * 512 + col];
  h[(size_t)row * 512 + col] = a;
  hbf[(size_t)row * 512 + col] = f2bf(a);
}

// ---------------- bf16 GEMM: A[M,K] x Bt[N,K]^T -> C[M,N] ----------------
// EPI: 0 f32; 1 f32+bias; 2 bf16+bias+relu; 3 bf16; 4 bf16+bias
template <int EPI, int BM, int BN, int BK>
__global__ __launch_bounds__(256) void gemm_bt(const short* __restrict__ A,
                                               const short* __restrict__ Bt,
                                               float* __restrict__ Cf, short* __restrict__ Cb,
                                               const float* __restrict__ bias,
                                               int M, int N, int K) {
  __shared__ short As[BM * BK];
  __shared__ short Bs[BN * BK];
  const int tid = threadIdx.x;
  const int wid = tid >> 6;
  const int lane = tid & 63;
  const int m0 = blockIdx.y * BM;
  const int n0 = blockIdx.x * BN;
  constexpr int WR = BM / 2, WC = BN / 2, FI = WR / 16, FJ = WC / 16, KK = BK / 32;
  const int wr = (wid >> 1) * WR;
  const int wc = (wid & 1) * WC;

  f32x4 acc[FI][FJ];
#pragma unroll
  for (int i = 0; i < FI; i++)
#pragma unroll
    for (int j = 0; j < FJ; j++)
#pragma unroll
      for (int q = 0; q < 4; q++) acc[i][j][q] = 0.0f;

  const short* aBase = A + (size_t)m0 * K;
  const short* bBase = Bt + (size_t)n0 * K;
  constexpr int RPC = 512 / BK;        // rows staged per gld_lds call (1024B)
  constexpr int CA = BM / RPC;         // calls for A tile
  constexpr int CT = (BM + BN) / RPC;  // total calls
  const int rowL = lane / (64 / RPC);        // lane's row within a call
  const int colE = (lane % (64 / RPC)) * 8;  // lane's 16B slot (in shorts)
  const int kg = (lane >> 4) * 8;
  const int r16 = lane & 15;

  for (int kt = 0; kt < K; kt += BK) {
    __syncthreads();
#pragma unroll
    for (int c = 0; c < CT / 4; ++c) {
      int s = c * 4 + wid;
      if (s < CA)
        gld_lds16(aBase + (size_t)(s * RPC + rowL) * K + kt + colE, As + s * 512);
      else
        gld_lds16(bBase + (size_t)((s - CA) * RPC + rowL) * K + kt + colE, Bs + (s - CA) * 512);
    }
    __syncthreads();
    bf16x8 af[FI][KK], bfr[FJ][KK];
#pragma unroll
    for (int i = 0; i < FI; i++)
#pragma unroll
      for (int kk = 0; kk < KK; kk++)
        af[i][kk] = *(const bf16x8*)&As[(wr + i * 16 + r16) * BK + kk * 32 + kg];
#pragma unroll
    for (int j = 0; j < FJ; j++)
#pragma unroll
      for (int kk = 0; kk < KK; kk++)
        bfr[j][kk] = *(const bf16x8*)&Bs[(wc + j * 16 + r16) * BK + kk * 32 + kg];
#pragma unroll
    for (int kk = 0; kk < KK; kk++)
#pragma unroll
      for (int i = 0; i < FI; i++)
#pragma unroll
        for (int j = 0; j < FJ; j++)
          acc[i][j] = __builtin_amdgcn_mfma_f32_16x16x32_bf16(af[i][kk], bfr[j][kk], acc[i][j], 0, 0, 0);
  }

  const int col16 = lane & 15;
  const int rowg = (lane >> 4) * 4;
#pragma unroll
  for (int i = 0; i < FI; i++) {
    int row = m0 + wr + i * 16 + rowg;
#pragma unroll
    for (int j = 0; j < FJ; j++) {
      int col = n0 + wc + j * 16 + col16;
      float bv = (EPI == 1 || EPI == 2 || EPI == 4) ? bias[col] : 0.0f;
#pragma unroll
      for (int q = 0; q < 4; q++) {
        float v = acc[i][j][q] + bv;
        if (EPI == 2) {
          v = fmaxf(v, 0.0f);
          Cb[(size_t)(row + q) * N + col] = f2bf(v);
        } else if (EPI == 3 || EPI == 4) {
          Cb[(size_t)(row + q) * N + col] = f2bf(v);
        } else {
          Cf[(size_t)(row + q) * N + col] = v;
        }
      }
    }
  }
}

// ---------------- scores + softmax + P write: per (b,h,64-query tile) ----------------
__global__ __launch_bounds__(256) void sm_kernel(const short* __restrict__ qkvh,
                                                 short* __restrict__ P) {
  const int bh = blockIdx.y, b = bh >> 3, h = bh & 7;
  const int q0 = blockIdx.x * 64;
  const int wid = threadIdx.x >> 6, lane = threadIdx.x & 63;
  const int r16 = lane & 15, g = lane >> 4;

  const short* qp = qkvh + (size_t)(b * 512 + q0 + wid * 16 + r16) * 1536 + h * 64 + g * 8;
  const bf16x8 qa0 = *(const bf16x8*)qp;
  const bf16x8 qa1 = *(const bf16x8*)(qp + 32);

  const short* kbase = qkvh + (size_t)(b * 512) * 1536 + 512 + h * 64 + g * 8;

  f32x4 acc[32];
#pragma unroll
  for (int tt = 0; tt < 32; ++tt) {
    const short* kp = kbase + (size_t)(tt * 16 + r16) * 1536;
    bf16x8 kb0 = *(const bf16x8*)kp;
    bf16x8 kb1 = *(const bf16x8*)(kp + 32);
    f32x4 c = {0.f, 0.f, 0.f, 0.f};
    c = __builtin_amdgcn_mfma_f32_16x16x32_bf16(qa0, kb0, c, 0, 0, 0);
    c = __builtin_amdgcn_mfma_f32_16x16x32_bf16(qa1, kb1, c, 0, 0, 0);
    acc[tt] = c;
  }

  float mx[4] = {-1e30f, -1e30f, -1e30f, -1e30f};
#pragma unroll
  for (int tt = 0; tt < 32; ++tt)
#pragma unroll
    for (int r = 0; r < 4; ++r) mx[r] = fmaxf(mx[r], acc[tt][r]);
#pragma unroll
  for (int r = 0; r < 4; ++r)
#pragma unroll
    for (int m = 8; m; m >>= 1) mx[r] = fmaxf(mx[r], __shfl_xor(mx[r], m, 16));

  float sum[4] = {0.f, 0.f, 0.f, 0.f};
#pragma unroll
  for (int tt = 0; tt < 32; ++tt)
#pragma unroll
    for (int r = 0; r < 4; ++r) {
      float e = __expf((acc[tt][r] - mx[r]) * 0.125f);
      sum[r] += e;
      acc[tt][r] = e;
    }
#pragma unroll
  for (int r = 0; r < 4; ++r)
#pragma unroll
    for (int m = 8; m; m >>= 1) sum[r] += __shfl_xor(sum[r], m, 16);
  float inv[4];
#pragma unroll
  for (int r = 0; r < 4; ++r) inv[r] = 1.0f / sum[r];

  short* prow = P + ((size_t)bh * 512 + q0 + wid * 16 + g * 4) * 512 + r16;
#pragma unroll
  for (int r = 0; r < 4; ++r)
#pragma unroll
    for (int tt = 0; tt < 32; ++tt)
      prow[(size_t)r * 512 + tt * 16] = f2bf(acc[tt][r] * inv[r]);
}

// ---------------- V transpose: qkvh V-section -> Vt[bh][64 dk][512 t] bf16 ----------------
__global__ __launch_bounds__(256) void vt_kernel(const short* __restrict__ qkvh,
                                                 short* __restrict__ Vt) {
  __shared__ short t[32][34];
  const int bh = blockIdx.z, b = bh >> 3, h = bh & 7;
  const int t0 = blockIdx.x * 32, d0 = blockIdx.y * 32;
  const int tx = threadIdx.x & 31, ty = threadIdx.x >> 5;  // 32 x 8
#pragma unroll
  for (int i = 0; i < 4; i++)
    t[ty + i * 8][tx] = qkvh[(size_t)(b * 512 + t0 + ty + i * 8) * 1536 + 1024 + h * 64 + d0 + tx];
  __syncthreads();
#pragma unroll
  for (int i = 0; i < 4; i++)
    Vt[((size_t)bh * 64 + d0 + ty + i * 8) * 512 + t0 + tx] = t[tx][ty + i * 8];
}

// ---------------- ctx = P @ V : per (b,h), tile 128x64 ----------------
__global__ __launch_bounds__(256) void pv_gemm(const short* __restrict__ P,
                                               const short* __restrict__ Vt,
                                               short* __restrict__ ctxb) {
  __shared__ short As[128 * 32];
  __shared__ short Bs[64 * 32];
  const int bh = blockIdx.y, b = bh >> 3, h = bh & 7;
  const int m0 = blockIdx.x * 128;
  const int tid = threadIdx.x, wid = tid >> 6, lane = tid & 63;
  const short* aBase = P + ((size_t)bh * 512 + m0) * 512;
  const short* bBase = Vt + (size_t)bh * 64 * 512;
  const int rowA0 = lane >> 2, colE = (lane & 3) * 8, kg = (lane >> 4) * 8, r16 = lane & 15;

  f32x4 acc[2][4];
#pragma unroll
  for (int i = 0; i < 2; i++)
#pragma unroll
    for (int j = 0; j < 4; j++)
#pragma unroll
      for (int q = 0; q < 4; q++) acc[i][j][q] = 0.0f;

  for (int kt = 0; kt < 512; kt += 32) {
    __syncthreads();
    gld_lds16(aBase + (size_t)(wid * 16 + rowA0) * 512 + kt + colE, As + wid * 512);
    gld_lds16(aBase + (size_t)((wid + 4) * 16 + rowA0) * 512 + kt + colE, As + (wid + 4) * 512);
    gld_lds16(bBase + (size_t)(wid * 16 + rowA0) * 512 + kt + colE, Bs + wid * 512);
    __syncthreads();
    bf16x8 af[2], bfr[4];
#pragma unroll
    for (int i = 0; i < 2; i++)
      af[i] = *(const bf16x8*)&As[(wid * 32 + i * 16 + r16) * 32 + kg];
#pragma unroll
    for (int j = 0; j < 4; j++)
      bfr[j] = *(const bf16x8*)&Bs[(j * 16 + r16) * 32 + kg];
#pragma unroll
    for (int i = 0; i < 2; i++)
#pragma unroll
      for (int j = 0; j < 4; j++)
        acc[i][j] = __builtin_amdgcn_mfma_f32_16x16x32_bf16(af[i], bfr[j], acc[i][j], 0, 0, 0);
  }

  const int rowg = (lane >> 4) * 4;
#pragma unroll
  for (int i = 0; i < 2; i++) {
    int row = m0 + wid * 32 + i * 16 + rowg;
#pragma unroll
    for (int j = 0; j < 4; j++) {
      int col = h * 64 + j * 16 + r16;
#pragma unroll
      for (int q = 0; q < 4; q++)
        ctxb[(size_t)(b * 512 + row + q) * 512 + col] = f2bf(acc[i][j][q]);
    }
  }
}

// ---------------- KL(avg_attn || uniform) per query row; one wave per row ----------------
__global__ __launch_bounds__(256) void kl_kernel(const short* __restrict__ P,
                                                 float* __restrict__ assoc) {
  const int wid = threadIdx.x >> 6, lane = threadIdx.x & 63;
  const int row = blockIdx.x * 4 + wid;  // b*512 + q
  const int b = row >> 9, q = row & 511;
  const float prior = 1.0f / 512.0f + 1e-8f;
  float hs[8] = {0.f, 0.f, 0.f, 0.f, 0.f, 0.f, 0.f, 0.f};
#pragma unroll
  for (int h = 0; h < 8; ++h) {
    bf16x8 v = *(const bf16x8*)&P[(((size_t)(b * 8 + h)) * 512 + q) * 512 + lane * 8];
#pragma unroll
    for (int k = 0; k < 8; ++k) hs[k] += bf2f((unsigned short)v[k]);
  }
  float s = 0.f;
#pragma unroll
  for (int k = 0; k < 8; ++k) {
    float a = hs[k] * 0.125f + 1e-8f;
    s += a * __logf(a / prior);
  }
#pragma unroll
  for (int m = 32; m; m >>= 1) s += __shfl_xor(s, m, 64);
  if (lane == 0) assoc[row] += s;
}

// ---------------- layernorm: h = LN(h + res_bf16)*g + b; fp32 + bf16 out ----------------
__global__ __launch_bounds__(256) void ln_kernel(const float* __restrict__ hin,
                                                 const short* __restrict__ res,
                                                 const float* __restrict__ g,
                                                 const float* __restrict__ bta,
                                                 float* __restrict__ hout, short* __restrict__ hbf) {
  const int wid = threadIdx.x >> 6, lane = threadIdx.x & 63;
  const size_t row = (size_t)blockIdx.x * 4 + wid;
  const float* hp = hin + row * 512;
  const short* rp = res + row * 512;
  float v[8], s = 0.f, s2 = 0.f;
#pragma unroll
  for (int i = 0; i < 8; i++) {
    int c = lane + i * 64;
    v[i] = hp[c] + bf2f((unsigned short)rp[c]);
    s += v[i];
    s2 += v[i] * v[i];
  }
#pragma unroll
  for (int m = 32; m; m >>= 1) {
    s += __shfl_xor(s, m, 64);
    s2 += __shfl_xor(s2, m, 64);
  }
  float mu = s * (1.0f / 512.0f);
  float var = s2 * (1.0f / 512.0f) - mu * mu;
  float rs = rsqrtf(var + 1e-5f);
#pragma unroll
  for (int i = 0; i < 8; i++) {
    int c = lane + i * 64;
    float y = (v[i] - mu) * rs * g[c] + bta[c];
    hout[row * 512 + c] = y;
    hbf[row * 512 + c] = f2bf(y);
  }
}

// ---------------- reconstruction via MFMA: out[4096,32] = h_bf @ WoutT^T + bout ----------------
__global__ __launch_bounds__(256) void recon_mfma(const short* __restrict__ hbf,
                                                  const short* __restrict__ WoutT,
                                                  const float* __restrict__ bout,
                                                  float* __restrict__ out) {
  const int wid = threadIdx.x >> 6, lane = threadIdx.x & 63;
  const int r16 = lane & 15, kg = (lane >> 4) * 8;
  const int wbase = blockIdx.x * 128 + wid * 32;

  f32x4 acc[2][2];
#pragma unroll
  for (int i = 0; i < 2; i++)
#pragma unroll
    for (int j = 0; j < 2; j++)
#pragma unroll
      for (int q = 0; q < 4; q++) acc[i][j][q] = 0.0f;

  for (int kt = 0; kt < 512; kt += 32) {
    bf16x8 af[2], bfr[2];
#pragma unroll
    for (int i = 0; i < 2; i++)
      af[i] = *(const bf16x8*)&hbf[(size_t)(wbase + i * 16 + r16) * 512 + kt + kg];
#pragma unroll
    for (int j = 0; j < 2; j++)
      bfr[j] = *(const bf16x8*)&WoutT[(size_t)(j * 16 + r16) * 512 + kt + kg];
#pragma unroll
    for (int i = 0; i < 2; i++)
#pragma unroll
      for (int j = 0; j < 2; j++)
        acc[i][j] = __builtin_amdgcn_mfma_f32_16x16x32_bf16(af[i], bfr[j], acc[i][j], 0, 0, 0);
  }

  const int rowg = (lane >> 4) * 4;
#pragma unroll
  for (int i = 0; i < 2; i++)
#pragma unroll
    for (int j = 0; j < 2; j++) {
      int col = j * 16 + r16;
#pragma unroll
      for (int q = 0; q < 4; q++)
        out[(size_t)(wbase + i * 16 + rowg + q) * 32 + col] = acc[i][j][q] + bout[col];
    }
}

// ---------------- score stage 2 + assoc output ----------------
__global__ __launch_bounds__(256) void score2_kernel(const short* __restrict__ s1,
                                                     const float* __restrict__ Ws2,
                                                     const float* __restrict__ bs2,
                                                     const float* __restrict__ assoc,
                                                     float* __restrict__ outScore,
                                                     float* __restrict__ outAssoc) {
  const int wid = threadIdx.x >> 6, lane = threadIdx.x & 63;
  const int row = blockIdx.x * 4 + wid;
  const short* rp = &s1[(size_t)row * 256 + lane * 4];
  float d = 0.f;
#pragma unroll
  for (int e = 0; e < 4; e++) d += bf2f((unsigned short)rp[e]) * Ws2[lane * 4 + e];
#pragma unroll
  for (int m = 32; m; m >>= 1) d += __shfl_xor(d, m, 64);
  if (lane == 0) {
    outScore[row] = 1.f / (1.f + __expf(-(d + bs2[0])));
    outAssoc[row] = assoc[row] * (1.0f / 6.0f);
  }
}

extern "C" void kernel_launch(void* const* d_in, const int* in_sizes, int n_in,
                              void* d_out, int out_size, void* d_ws, size_t ws_size,
                              hipStream_t stream) {
  const float* x    = (const float*)d_in[0];
  const float* W_in = (const float*)d_in[1];
  const float* b_in = (const float*)d_in[2];
  const float* pe   = (const float*)d_in[3];
  const float* Wq   = (const float*)d_in[4];
  const float* Wk   = (const float*)d_in[5];
  const float* Wv   = (const float*)d_in[6];
  const float* Wo   = (const float*)d_in[7];
  const float* bo   = (const float*)d_in[8];
  const float* W1   = (const float*)d_in[9];
  const float* b1   = (const float*)d_in[10];
  const float* W2   = (const float*)d_in[11];
  const float* b2   = (const float*)d_in[12];
  const float* ln1g = (const float*)d_in[13];
  const float* ln1b = (const float*)d_in[14];
  const float* ln2g = (const float*)d_in[15];
  const float* ln2b = (const float*)d_in[16];
  const float* Wout = (const float*)d_in[17];
  const float* bout = (const float*)d_in[18];
  const float* Ws1  = (const float*)d_in[19];
  const float* bs1  = (const float*)d_in[20];
  const float* Ws2  = (const float*)d_in[21];
  const float* bs2  = (const float*)d_in[22];

  char* p = (char*)d_ws;
  auto alloc = [&](size_t bytes) {
    void* r = (void*)p;
    p += (bytes + 255) & ~(size_t)255;
    return r;
  };
  float* h     = (float*)alloc((size_t)4096 * 512 * 4);
  short* h_bf  = (short*)alloc((size_t)4096 * 512 * 2);
  short* qkvh  = (short*)alloc((size_t)4096 * 1536 * 2);
  short* aout  = (short*)alloc((size_t)4096 * 512 * 2);
  short* ctxb  = (short*)alloc((size_t)4096 * 512 * 2);
  short* ff1b  = (short*)alloc((size_t)4096 * 2048 * 2);
  short* ff2   = (short*)alloc((size_t)4096 * 512 * 2);
  float* assoc = (float*)alloc((size_t)4096 * 4);
  short* Pbuf  = (short*)alloc((size_t)64 * 512 * 512 * 2);
  short* Vt    = (short*)alloc((size_t)64 * 64 * 512 * 2);
  short* sc1   = (short*)alloc((size_t)4096 * 256 * 2);
  short* qkvt  = (short*)alloc((size_t)6 * 1536 * 512 * 2);
  short* wot   = (short*)alloc((size_t)6 * 512 * 512 * 2);
  short* w1t   = (short*)alloc((size_t)6 * 2048 * 512 * 2);
  short* w2t   = (short*)alloc((size_t)6 * 512 * 2048 * 2);
  short* ws1t  = (short*)alloc((size_t)256 * 512 * 2);
  short* woutT = (short*)alloc((size_t)32 * 512 * 2);

  // weight transpose+convert (per launch; graph-capture safe)
  transpose_qkv<<<dim3(16, 16, 18), 256, 0, stream>>>(Wq, Wk, Wv, qkvt);
  transpose_bf<<<dim3(16, 16, 6), 256, 0, stream>>>(Wo, wot, 512, 512, 262144, 262144);
  transpose_bf<<<dim3(64, 16, 6), 256, 0, stream>>>(W1, w1t, 512, 2048, 1048576, 1048576);
  transpose_bf<<<dim3(16, 64, 6), 256, 0, stream>>>(W2, w2t, 2048, 512, 1048576, 1048576);
  transpose_bf<<<dim3(8, 16, 1), 256, 0, stream>>>(Ws1, ws1t, 512, 256, 0, 0);
  transpose_bf<<<dim3(1, 16, 1), 256, 0, stream>>>(Wout, woutT, 512, 32, 0, 0);

  hipMemsetAsync(assoc, 0, 4096 * 4, stream);
  embed_kernel<<<8192, 256, 0, stream>>>(x, W_in, b_in, pe, h, h_bf);

  for (int l = 0; l < 6; ++l) {
    gemm_bt<3, 128, 128, 64><<<dim3(12, 32), 256, 0, stream>>>(
        h_bf, qkvt + (size_t)l * 786432, nullptr, qkvh, nullptr, 4096, 1536, 512);
    vt_kernel<<<dim3(16, 2, 64), 256, 0, stream>>>(qkvh, Vt);
    sm_kernel<<<dim3(8, 64), 256, 0, stream>>>(qkvh, Pbuf);
    pv_gemm<<<dim3(4, 64), 256, 0, stream>>>(Pbuf, Vt, ctxb);
    kl_kernel<<<1024, 256, 0, stream>>>(Pbuf, assoc);
    gemm_bt<4, 128, 64, 64><<<dim3(8, 32), 256, 0, stream>>>(
        ctxb, wot + (size_t)l * 262144, nullptr, aout, bo + l * 512, 4096, 512, 512);
    ln_kernel<<<1024, 256, 0, stream>>>(h, aout, ln1g + l * 512, ln1b + l * 512, h, h_bf);
    gemm_bt<2, 128, 128, 64><<<dim3(16, 32), 256, 0, stream>>>(
        h_bf, w1t + (size_t)l * 1048576, nullptr, ff1b, b1 + l * 2048, 4096, 2048, 512);
    gemm_bt<4, 128, 64, 64><<<dim3(8, 32), 256, 0, stream>>>(
        ff1b, w2t + (size_t)l * 1048576, nullptr, ff2, b2 + l * 512, 4096, 512, 2048);
    ln_kernel<<<1024, 256, 0, stream>>>(h, ff2, ln2g + l * 512, ln2b + l * 512, h, h_bf);
  }

  float* out = (float*)d_out;
  recon_mfma<<<32, 256, 0, stream>>>(h_bf, woutT, bout, out);
  gemm_bt<2, 128, 128, 64><<<dim3(2, 32), 256, 0, stream>>>(h_bf, ws1t, nullptr, sc1, bs1,
                                                            4096, 256, 512);
  score2_kernel<<<1024, 256, 0, stream>>>(sc1, Ws2, bs2, assoc, out + 131072,
                                          out + 131072 + 4096);
}

// Round 5
// 887.260 us; speedup vs baseline: 1.1153x; 1.1153x over previous
//
#include <hip/hip_runtime.h>
#include <math.h>

typedef __attribute__((ext_vector_type(8))) short bf16x8;
typedef __attribute__((ext_vector_type(4))) float f32x4;

__device__ __forceinline__ short f2bf(float v) {
  union { float f; unsigned u; } x; x.f = v;
  unsigned r = x.u + 0x7fffu + ((x.u >> 16) & 1u);
  return (short)(r >> 16);
}

__device__ __forceinline__ float bf2f(unsigned short u) {
  union { unsigned u; float f; } x; x.u = ((unsigned)u) << 16;
  return x.f;
}

__device__ __forceinline__ void gld_lds16(const void* g, void* l) {
  __builtin_amdgcn_global_load_lds((const __attribute__((address_space(1))) void*)g,
                                   (__attribute__((address_space(3))) void*)l, 16, 0, 0);
}

// ---------------- transpose fp32 [R,C] -> bf16 [C,R], batched over z ----------------
__global__ __launch_bounds__(256) void transpose_bf(const float* __restrict__ src,
                                                    short* __restrict__ dst,
                                                    int R, int C, size_t sStride, size_t dStride) {
  __shared__ float t[32][33];
  src += blockIdx.z * sStride;
  dst += blockIdx.z * dStride;
  int tx = threadIdx.x & 31, ty = threadIdx.x >> 5;  // 32 x 8
  int c0 = blockIdx.x * 32, r0 = blockIdx.y * 32;
#pragma unroll
  for (int i = 0; i < 4; i++)
    t[ty + i * 8][tx] = src[(size_t)(r0 + ty + i * 8) * C + c0 + tx];
  __syncthreads();
#pragma unroll
  for (int i = 0; i < 4; i++)
    dst[(size_t)(c0 + ty + i * 8) * R + r0 + tx] = f2bf(t[tx][ty + i * 8]);
}

// ---------------- transpose Wq/Wk/Wv [512,512] fp32 -> qkvt bf16, one dispatch ----------------
__global__ __launch_bounds__(256) void transpose_qkv(const float* __restrict__ Wq,
                                                     const float* __restrict__ Wk,
                                                     const float* __restrict__ Wv,
                                                     short* __restrict__ qkvt) {
  __shared__ float t[32][33];
  const int z = blockIdx.z;           // 0..17
  const int which = z / 6, l = z % 6;
  const float* src = (which == 0 ? Wq : which == 1 ? Wk : Wv) + (size_t)l * 262144;
  short* dst = qkvt + (size_t)l * 786432 + (size_t)which * 262144;
  int tx = threadIdx.x & 31, ty = threadIdx.x >> 5;
  int c0 = blockIdx.x * 32, r0 = blockIdx.y * 32;
#pragma unroll
  for (int i = 0; i < 4; i++)
    t[ty + i * 8][tx] = src[(size_t)(r0 + ty + i * 8) * 512 + c0 + tx];
  __syncthreads();
#pragma unroll
  for (int i = 0; i < 4; i++)
    dst[(size_t)(c0 + ty + i * 8) * 512 + r0 + tx] = f2bf(t[tx][ty + i * 8]);
}

// ---------------- embed: h = x @ W_in + b_in + pe; also bf16 copy ----------------
__global__ void embed_kernel(const float* __restrict__ x, const float* __restrict__ W_in,
                             const float* __restrict__ b_in, const float* __restrict__ pe,
                             float* __restrict__ h, short* __restrict__ hbf) {
  int col = (blockIdx.x & 1) * 256 + threadIdx.x;
  int row = blockIdx.x >> 1;
  int s = row & 511;
  float a = b_in[col] + pe[s * 512 + col];
  const float* xr = x + (size_t)row * 32;
#pragma unroll
  for (int k = 0; k < 32; k++) a += xr[k] * W_in[k * 512 + col];
  h[(size_t)row * 512 + col] = a;
  hbf[(size_t)row * 512 + col] = f2bf(a);
}

// ---------------- bf16 GEMM: A[M,K] x Bt[N,K]^T -> C[M,N] ----------------
// EPI: 0 f32; 1 f32+bias; 2 bf16+bias+relu; 3 bf16; 4 bf16+bias
// BK=32: LDS row stride 64B -> only 2-way bank aliasing on ds_read_b128 (free per m136).
// BK=64 measured 4.7M conflicts/dispatch (32-way, 128B stride) -> do not raise BK.
template <int EPI, int BM, int BN, int BK>
__global__ __launch_bounds__(256) void gemm_bt(const short* __restrict__ A,
                                               const short* __restrict__ Bt,
                                               float* __restrict__ Cf, short* __restrict__ Cb,
                                               const float* __restrict__ bias,
                                               int M, int N, int K) {
  __shared__ short As[BM * BK];
  __shared__ short Bs[BN * BK];
  const int tid = threadIdx.x;
  const int wid = tid >> 6;
  const int lane = tid & 63;
  const int m0 = blockIdx.y * BM;
  const int n0 = blockIdx.x * BN;
  constexpr int WR = BM / 2, WC = BN / 2, FI = WR / 16, FJ = WC / 16, KK = BK / 32;
  const int wr = (wid >> 1) * WR;
  const int wc = (wid & 1) * WC;

  f32x4 acc[FI][FJ];
#pragma unroll
  for (int i = 0; i < FI; i++)
#pragma unroll
    for (int j = 0; j < FJ; j++)
#pragma unroll
      for (int q = 0; q < 4; q++) acc[i][j][q] = 0.0f;

  const short* aBase = A + (size_t)m0 * K;
  const short* bBase = Bt + (size_t)n0 * K;
  constexpr int RPC = 512 / BK;        // rows staged per gld_lds call (1024B)
  constexpr int CA = BM / RPC;         // calls for A tile
  constexpr int CT = (BM + BN) / RPC;  // total calls
  const int rowL = lane / (64 / RPC);        // lane's row within a call
  const int colE = (lane % (64 / RPC)) * 8;  // lane's 16B slot (in shorts)
  const int kg = (lane >> 4) * 8;
  const int r16 = lane & 15;

  for (int kt = 0; kt < K; kt += BK) {
    __syncthreads();
#pragma unroll
    for (int c = 0; c < CT / 4; ++c) {
      int s = c * 4 + wid;
      if (s < CA)
        gld_lds16(aBase + (size_t)(s * RPC + rowL) * K + kt + colE, As + s * 512);
      else
        gld_lds16(bBase + (size_t)((s - CA) * RPC + rowL) * K + kt + colE, Bs + (s - CA) * 512);
    }
    __syncthreads();
    bf16x8 af[FI][KK], bfr[FJ][KK];
#pragma unroll
    for (int i = 0; i < FI; i++)
#pragma unroll
      for (int kk = 0; kk < KK; kk++)
        af[i][kk] = *(const bf16x8*)&As[(wr + i * 16 + r16) * BK + kk * 32 + kg];
#pragma unroll
    for (int j = 0; j < FJ; j++)
#pragma unroll
      for (int kk = 0; kk < KK; kk++)
        bfr[j][kk] = *(const bf16x8*)&Bs[(wc + j * 16 + r16) * BK + kk * 32 + kg];
#pragma unroll
    for (int kk = 0; kk < KK; kk++)
#pragma unroll
      for (int i = 0; i < FI; i++)
#pragma unroll
        for (int j = 0; j < FJ; j++)
          acc[i][j] = __builtin_amdgcn_mfma_f32_16x16x32_bf16(af[i][kk], bfr[j][kk], acc[i][j], 0, 0, 0);
  }

  const int col16 = lane & 15;
  const int rowg = (lane >> 4) * 4;
#pragma unroll
  for (int i = 0; i < FI; i++) {
    int row = m0 + wr + i * 16 + rowg;
#pragma unroll
    for (int j = 0; j < FJ; j++) {
      int col = n0 + wc + j * 16 + col16;
      float bv = (EPI == 1 || EPI == 2 || EPI == 4) ? bias[col] : 0.0f;
#pragma unroll
      for (int q = 0; q < 4; q++) {
        float v = acc[i][j][q] + bv;
        if (EPI == 2) {
          v = fmaxf(v, 0.0f);
          Cb[(size_t)(row + q) * N + col] = f2bf(v);
        } else if (EPI == 3 || EPI == 4) {
          Cb[(size_t)(row + q) * N + col] = f2bf(v);
        } else {
          Cf[(size_t)(row + q) * N + col] = v;
        }
      }
    }
  }
}

// ---------------- scores + softmax + P write: per (b,h,64-query tile) ----------------
__global__ __launch_bounds__(256) void sm_kernel(const short* __restrict__ qkvh,
                                                 short* __restrict__ P) {
  const int bh = blockIdx.y, b = bh >> 3, h = bh & 7;
  const int q0 = blockIdx.x * 64;
  const int wid = threadIdx.x >> 6, lane = threadIdx.x & 63;
  const int r16 = lane & 15, g = lane >> 4;

  const short* qp = qkvh + (size_t)(b * 512 + q0 + wid * 16 + r16) * 1536 + h * 64 + g * 8;
  const bf16x8 qa0 = *(const bf16x8*)qp;
  const bf16x8 qa1 = *(const bf16x8*)(qp + 32);

  const short* kbase = qkvh + (size_t)(b * 512) * 1536 + 512 + h * 64 + g * 8;

  f32x4 acc[32];
#pragma unroll
  for (int tt = 0; tt < 32; ++tt) {
    const short* kp = kbase + (size_t)(tt * 16 + r16) * 1536;
    bf16x8 kb0 = *(const bf16x8*)kp;
    bf16x8 kb1 = *(const bf16x8*)(kp + 32);
    f32x4 c = {0.f, 0.f, 0.f, 0.f};
    c = __builtin_amdgcn_mfma_f32_16x16x32_bf16(qa0, kb0, c, 0, 0, 0);
    c = __builtin_amdgcn_mfma_f32_16x16x32_bf16(qa1, kb1, c, 0, 0, 0);
    acc[tt] = c;
  }

  float mx[4] = {-1e30f, -1e30f, -1e30f, -1e30f};
#pragma unroll
  for (int tt = 0; tt < 32; ++tt)
#pragma unroll
    for (int r = 0; r < 4; ++r) mx[r] = fmaxf(mx[r], acc[tt][r]);
#pragma unroll
  for (int r = 0; r < 4; ++r)
#pragma unroll
    for (int m = 8; m; m >>= 1) mx[r] = fmaxf(mx[r], __shfl_xor(mx[r], m, 16));

  float sum[4] = {0.f, 0.f, 0.f, 0.f};
#pragma unroll
  for (int tt = 0; tt < 32; ++tt)
#pragma unroll
    for (int r = 0; r < 4; ++r) {
      float e = __expf((acc[tt][r] - mx[r]) * 0.125f);
      sum[r] += e;
      acc[tt][r] = e;
    }
#pragma unroll
  for (int r = 0; r < 4; ++r)
#pragma unroll
    for (int m = 8; m; m >>= 1) sum[r] += __shfl_xor(sum[r], m, 16);
  float inv[4];
#pragma unroll
  for (int r = 0; r < 4; ++r) inv[r] = 1.0f / sum[r];

  short* prow = P + ((size_t)bh * 512 + q0 + wid * 16 + g * 4) * 512 + r16;
#pragma unroll
  for (int r = 0; r < 4; ++r)
#pragma unroll
    for (int tt = 0; tt < 32; ++tt)
      prow[(size_t)r * 512 + tt * 16] = f2bf(acc[tt][r] * inv[r]);
}

// ---------------- V transpose: qkvh V-section -> Vt[bh][64 dk][512 t] bf16 ----------------
__global__ __launch_bounds__(256) void vt_kernel(const short* __restrict__ qkvh,
                                                 short* __restrict__ Vt) {
  __shared__ short t[32][34];
  const int bh = blockIdx.z, b = bh >> 3, h = bh & 7;
  const int t0 = blockIdx.x * 32, d0 = blockIdx.y * 32;
  const int tx = threadIdx.x & 31, ty = threadIdx.x >> 5;  // 32 x 8
#pragma unroll
  for (int i = 0; i < 4; i++)
    t[ty + i * 8][tx] = qkvh[(size_t)(b * 512 + t0 + ty + i * 8) * 1536 + 1024 + h * 64 + d0 + tx];
  __syncthreads();
#pragma unroll
  for (int i = 0; i < 4; i++)
    Vt[((size_t)bh * 64 + d0 + ty + i * 8) * 512 + t0 + tx] = t[tx][ty + i * 8];
}

// ---------------- ctx = P @ V : per (b,h), tile 128x64 ----------------
__global__ __launch_bounds__(256) void pv_gemm(const short* __restrict__ P,
                                               const short* __restrict__ Vt,
                                               short* __restrict__ ctxb) {
  __shared__ short As[128 * 32];
  __shared__ short Bs[64 * 32];
  const int bh = blockIdx.y, b = bh >> 3, h = bh & 7;
  const int m0 = blockIdx.x * 128;
  const int tid = threadIdx.x, wid = tid >> 6, lane = tid & 63;
  const short* aBase = P + ((size_t)bh * 512 + m0) * 512;
  const short* bBase = Vt + (size_t)bh * 64 * 512;
  const int rowA0 = lane >> 2, colE = (lane & 3) * 8, kg = (lane >> 4) * 8, r16 = lane & 15;

  f32x4 acc[2][4];
#pragma unroll
  for (int i = 0; i < 2; i++)
#pragma unroll
    for (int j = 0; j < 4; j++)
#pragma unroll
      for (int q = 0; q < 4; q++) acc[i][j][q] = 0.0f;

  for (int kt = 0; kt < 512; kt += 32) {
    __syncthreads();
    gld_lds16(aBase + (size_t)(wid * 16 + rowA0) * 512 + kt + colE, As + wid * 512);
    gld_lds16(aBase + (size_t)((wid + 4) * 16 + rowA0) * 512 + kt + colE, As + (wid + 4) * 512);
    gld_lds16(bBase + (size_t)(wid * 16 + rowA0) * 512 + kt + colE, Bs + wid * 512);
    __syncthreads();
    bf16x8 af[2], bfr[4];
#pragma unroll
    for (int i = 0; i < 2; i++)
      af[i] = *(const bf16x8*)&As[(wid * 32 + i * 16 + r16) * 32 + kg];
#pragma unroll
    for (int j = 0; j < 4; j++)
      bfr[j] = *(const bf16x8*)&Bs[(j * 16 + r16) * 32 + kg];
#pragma unroll
    for (int i = 0; i < 2; i++)
#pragma unroll
      for (int j = 0; j < 4; j++)
        acc[i][j] = __builtin_amdgcn_mfma_f32_16x16x32_bf16(af[i], bfr[j], acc[i][j], 0, 0, 0);
  }

  const int rowg = (lane >> 4) * 4;
#pragma unroll
  for (int i = 0; i < 2; i++) {
    int row = m0 + wid * 32 + i * 16 + rowg;
#pragma unroll
    for (int j = 0; j < 4; j++) {
      int col = h * 64 + j * 16 + r16;
#pragma unroll
      for (int q = 0; q < 4; q++)
        ctxb[(size_t)(b * 512 + row + q) * 512 + col] = f2bf(acc[i][j][q]);
    }
  }
}

// ---------------- KL(avg_attn || uniform) per query row; one wave per row ----------------
template <int FIRST>
__global__ __launch_bounds__(256) void kl_kernel(const short* __restrict__ P,
                                                 float* __restrict__ assoc) {
  const int wid = threadIdx.x >> 6, lane = threadIdx.x & 63;
  const int row = blockIdx.x * 4 + wid;  // b*512 + q
  const int b = row >> 9, q = row & 511;
  const float prior = 1.0f / 512.0f + 1e-8f;
  float hs[8] = {0.f, 0.f, 0.f, 0.f, 0.f, 0.f, 0.f, 0.f};
#pragma unroll
  for (int h = 0; h < 8; ++h) {
    bf16x8 v = *(const bf16x8*)&P[(((size_t)(b * 8 + h)) * 512 + q) * 512 + lane * 8];
#pragma unroll
    for (int k = 0; k < 8; ++k) hs[k] += bf2f((unsigned short)v[k]);
  }
  float s = 0.f;
#pragma unroll
  for (int k = 0; k < 8; ++k) {
    float a = hs[k] * 0.125f + 1e-8f;
    s += a * __logf(a / prior);
  }
#pragma unroll
  for (int m = 32; m; m >>= 1) s += __shfl_xor(s, m, 64);
  if (lane == 0) assoc[row] = FIRST ? s : (assoc[row] + s);
}

// ---------------- layernorm: h = LN(h + res_bf16)*g + b; fp32 + bf16 out ----------------
__global__ __launch_bounds__(256) void ln_kernel(const float* __restrict__ hin,
                                                 const short* __restrict__ res,
                                                 const float* __restrict__ g,
                                                 const float* __restrict__ bta,
                                                 float* __restrict__ hout, short* __restrict__ hbf) {
  const int wid = threadIdx.x >> 6, lane = threadIdx.x & 63;
  const size_t row = (size_t)blockIdx.x * 4 + wid;
  const float* hp = hin + row * 512;
  const short* rp = res + row * 512;
  float v[8], s = 0.f, s2 = 0.f;
#pragma unroll
  for (int i = 0; i < 8; i++) {
    int c = lane + i * 64;
    v[i] = hp[c] + bf2f((unsigned short)rp[c]);
    s += v[i];
    s2 += v[i] * v[i];
  }
#pragma unroll
  for (int m = 32; m; m >>= 1) {
    s += __shfl_xor(s, m, 64);
    s2 += __shfl_xor(s2, m, 64);
  }
  float mu = s * (1.0f / 512.0f);
  float var = s2 * (1.0f / 512.0f) - mu * mu;
  float rs = rsqrtf(var + 1e-5f);
#pragma unroll
  for (int i = 0; i < 8; i++) {
    int c = lane + i * 64;
    float y = (v[i] - mu) * rs * g[c] + bta[c];
    hout[row * 512 + c] = y;
    hbf[row * 512 + c] = f2bf(y);
  }
}

// ---------------- reconstruction via MFMA: out[4096,32] = h_bf @ WoutT^T + bout ----------------
__global__ __launch_bounds__(256) void recon_mfma(const short* __restrict__ hbf,
                                                  const short* __restrict__ WoutT,
                                                  const float* __restrict__ bout,
                                                  float* __restrict__ out) {
  const int wid = threadIdx.x >> 6, lane = threadIdx.x & 63;
  const int r16 = lane & 15, kg = (lane >> 4) * 8;
  const int wbase = blockIdx.x * 128 + wid * 32;

  f32x4 acc[2][2];
#pragma unroll
  for (int i = 0; i < 2; i++)
#pragma unroll
    for (int j = 0; j < 2; j++)
#pragma unroll
      for (int q = 0; q < 4; q++) acc[i][j][q] = 0.0f;

  for (int kt = 0; kt < 512; kt += 32) {
    bf16x8 af[2], bfr[2];
#pragma unroll
    for (int i = 0; i < 2; i++)
      af[i] = *(const bf16x8*)&hbf[(size_t)(wbase + i * 16 + r16) * 512 + kt + kg];
#pragma unroll
    for (int j = 0; j < 2; j++)
      bfr[j] = *(const bf16x8*)&WoutT[(size_t)(j * 16 + r16) * 512 + kt + kg];
#pragma unroll
    for (int i = 0; i < 2; i++)
#pragma unroll
      for (int j = 0; j < 2; j++)
        acc[i][j] = __builtin_amdgcn_mfma_f32_16x16x32_bf16(af[i], bfr[j], acc[i][j], 0, 0, 0);
  }

  const int rowg = (lane >> 4) * 4;
#pragma unroll
  for (int i = 0; i < 2; i++)
#pragma unroll
    for (int j = 0; j < 2; j++) {
      int col = j * 16 + r16;
#pragma unroll
      for (int q = 0; q < 4; q++)
        out[(size_t)(wbase + i * 16 + rowg + q) * 32 + col] = acc[i][j][q] + bout[col];
    }
}

// ---------------- score stage 2 + assoc output ----------------
__global__ __launch_bounds__(256) void score2_kernel(const short* __restrict__ s1,
                                                     const float* __restrict__ Ws2,
                                                     const float* __restrict__ bs2,
                                                     const float* __restrict__ assoc,
                                                     float* __restrict__ outScore,
                                                     float* __restrict__ outAssoc) {
  const int wid = threadIdx.x >> 6, lane = threadIdx.x & 63;
  const int row = blockIdx.x * 4 + wid;
  const short* rp = &s1[(size_t)row * 256 + lane * 4];
  float d = 0.f;
#pragma unroll
  for (int e = 0; e < 4; e++) d += bf2f((unsigned short)rp[e]) * Ws2[lane * 4 + e];
#pragma unroll
  for (int m = 32; m; m >>= 1) d += __shfl_xor(d, m, 64);
  if (lane == 0) {
    outScore[row] = 1.f / (1.f + __expf(-(d + bs2[0])));
    outAssoc[row] = assoc[row] * (1.0f / 6.0f);
  }
}

extern "C" void kernel_launch(void* const* d_in, const int* in_sizes, int n_in,
                              void* d_out, int out_size, void* d_ws, size_t ws_size,
                              hipStream_t stream) {
  const float* x    = (const float*)d_in[0];
  const float* W_in = (const float*)d_in[1];
  const float* b_in = (const float*)d_in[2];
  const float* pe   = (const float*)d_in[3];
  const float* Wq   = (const float*)d_in[4];
  const float* Wk   = (const float*)d_in[5];
  const float* Wv   = (const float*)d_in[6];
  const float* Wo   = (const float*)d_in[7];
  const float* bo   = (const float*)d_in[8];
  const float* W1   = (const float*)d_in[9];
  const float* b1   = (const float*)d_in[10];
  const float* W2   = (const float*)d_in[11];
  const float* b2   = (const float*)d_in[12];
  const float* ln1g = (const float*)d_in[13];
  const float* ln1b = (const float*)d_in[14];
  const float* ln2g = (const float*)d_in[15];
  const float* ln2b = (const float*)d_in[16];
  const float* Wout = (const float*)d_in[17];
  const float* bout = (const float*)d_in[18];
  const float* Ws1  = (const float*)d_in[19];
  const float* bs1  = (const float*)d_in[20];
  const float* Ws2  = (const float*)d_in[21];
  const float* bs2  = (const float*)d_in[22];

  char* p = (char*)d_ws;
  auto alloc = [&](size_t bytes) {
    void* r = (void*)p;
    p += (bytes + 255) & ~(size_t)255;
    return r;
  };
  float* h     = (float*)alloc((size_t)4096 * 512 * 4);
  short* h_bf  = (short*)alloc((size_t)4096 * 512 * 2);
  short* qkvh  = (short*)alloc((size_t)4096 * 1536 * 2);
  short* aout  = (short*)alloc((size_t)4096 * 512 * 2);
  short* ctxb  = (short*)alloc((size_t)4096 * 512 * 2);
  short* ff1b  = (short*)alloc((size_t)4096 * 2048 * 2);
  short* ff2   = (short*)alloc((size_t)4096 * 512 * 2);
  float* assoc = (float*)alloc((size_t)4096 * 4);
  short* Pbuf  = (short*)alloc((size_t)64 * 512 * 512 * 2);
  short* Vt    = (short*)alloc((size_t)64 * 64 * 512 * 2);
  short* sc1   = (short*)alloc((size_t)4096 * 256 * 2);
  short* qkvt  = (short*)alloc((size_t)6 * 1536 * 512 * 2);
  short* wot   = (short*)alloc((size_t)6 * 512 * 512 * 2);
  short* w1t   = (short*)alloc((size_t)6 * 2048 * 512 * 2);
  short* w2t   = (short*)alloc((size_t)6 * 512 * 2048 * 2);
  short* ws1t  = (short*)alloc((size_t)256 * 512 * 2);
  short* woutT = (short*)alloc((size_t)32 * 512 * 2);

  // weight transpose+convert (per launch; graph-capture safe)
  transpose_qkv<<<dim3(16, 16, 18), 256, 0, stream>>>(Wq, Wk, Wv, qkvt);
  transpose_bf<<<dim3(16, 16, 6), 256, 0, stream>>>(Wo, wot, 512, 512, 262144, 262144);
  transpose_bf<<<dim3(64, 16, 6), 256, 0, stream>>>(W1, w1t, 512, 2048, 1048576, 1048576);
  transpose_bf<<<dim3(16, 64, 6), 256, 0, stream>>>(W2, w2t, 2048, 512, 1048576, 1048576);
  transpose_bf<<<dim3(8, 16, 1), 256, 0, stream>>>(Ws1, ws1t, 512, 256, 0, 0);
  transpose_bf<<<dim3(1, 16, 1), 256, 0, stream>>>(Wout, woutT, 512, 32, 0, 0);

  embed_kernel<<<8192, 256, 0, stream>>>(x, W_in, b_in, pe, h, h_bf);

  for (int l = 0; l < 6; ++l) {
    gemm_bt<3, 128, 128, 32><<<dim3(12, 32), 256, 0, stream>>>(
        h_bf, qkvt + (size_t)l * 786432, nullptr, qkvh, nullptr, 4096, 1536, 512);
    vt_kernel<<<dim3(16, 2, 64), 256, 0, stream>>>(qkvh, Vt);
    sm_kernel<<<dim3(8, 64), 256, 0, stream>>>(qkvh, Pbuf);
    pv_gemm<<<dim3(4, 64), 256, 0, stream>>>(Pbuf, Vt, ctxb);
    if (l == 0)
      kl_kernel<1><<<1024, 256, 0, stream>>>(Pbuf, assoc);
    else
      kl_kernel<0><<<1024, 256, 0, stream>>>(Pbuf, assoc);
    gemm_bt<4, 64, 64, 32><<<dim3(8, 64), 256, 0, stream>>>(
        ctxb, wot + (size_t)l * 262144, nullptr, aout, bo + l * 512, 4096, 512, 512);
    ln_kernel<<<1024, 256, 0, stream>>>(h, aout, ln1g + l * 512, ln1b + l * 512, h, h_bf);
    gemm_bt<2, 128, 128, 32><<<dim3(16, 32), 256, 0, stream>>>(
        h_bf, w1t + (size_t)l * 1048576, nullptr, ff1b, b1 + l * 2048, 4096, 2048, 512);
    gemm_bt<4, 64, 64, 32><<<dim3(8, 64), 256, 0, stream>>>(
        ff1b, w2t + (size_t)l * 1048576, nullptr, ff2, b2 + l * 512, 4096, 512, 2048);
    ln_kernel<<<1024, 256, 0, stream>>>(h, ff2, ln2g + l * 512, ln2b + l * 512, h, h_bf);
  }

  float* out = (float*)d_out;
  recon_mfma<<<32, 256, 0, stream>>>(h_bf, woutT, bout, out);
  gemm_bt<2, 128, 128, 32><<<dim3(2, 32), 256, 0, stream>>>(h_bf, ws1t, nullptr, sc1, bs1,
                                                            4096, 256, 512);
  score2_kernel<<<1024, 256, 0, stream>>>(sc1, Ws2, bs2, assoc, out + 131072,
                                          out + 131072 + 4096);
}